// Round 2
// baseline (208.336 us; speedup 1.0000x reference)
//
#include <hip/hip_runtime.h>
#include <hip/hip_bf16.h>
#include <stdint.h>

// Fastfood 2D conv, MI355X. fp32 I/O per reference:
// input (16,256,32,32) f32, B/G/S (1,4096) f32, bias (512) f32, P (4096) i32.
// Output (16,512,32,32) f32.
// Per pixel: patch j=kk*256+ch (2304, pad to 4096), *B, FWHT4096, perm P, *G,
// FWHT4096, *S[0:512]+bias.
//
// FWHT4096 = H16 (x3, radix-16): thread t=(t1*16+t0) holds 16 regs.
//  round A: j = r*256 + t        (r = kk at build time -> patch gather is natural)
//  round B: j = t1*256 + r*16 + t0
//  round C: j = t1*256 + t0*16 + r  (j = 16t + r -> outputs j<512 live in t<32)
// LDS exchange buffer uses XOR swizzle sigma(j) = j ^ ((j>>5)&7) ^ 24*j8 ^ 8*j9:
// all exchange patterns are exactly 2 lanes/bank (free per m136), size stays 4096.
// Input patches cached in LDS as bf16 (fp32 would blow the 64 KiB block limit);
// 2^-9 relative rounding is far inside the 2%-of-max threshold.

__device__ __forceinline__ float bf2f(uint16_t u) {
    union { uint32_t i; float f; } c; c.i = ((uint32_t)u) << 16; return c.f;
}

__device__ __forceinline__ uint16_t f2bf(float f) {  // round-nearest-even
    uint32_t u = __float_as_uint(f);
    return (uint16_t)((u + 0x7FFFu + ((u >> 16) & 1u)) >> 16);
}

__device__ __forceinline__ int swz(int j) {
    return j ^ ((j >> 5) & 7) ^ (((j >> 8) & 1) * 24) ^ (((j >> 9) & 1) * 8);
}

__device__ __forceinline__ void h16(float* x) {
    #pragma unroll
    for (int h = 1; h < 16; h <<= 1) {
        #pragma unroll
        for (int g = 0; g < 16; g += 2 * h) {
            #pragma unroll
            for (int u = g; u < g + h; ++u) {
                float a = x[u], b = x[u + h];
                x[u] = a + b; x[u + h] = a - b;
            }
        }
    }
}

__global__ __launch_bounds__(256, 2)
void fastfood_kernel(const float* __restrict__ in,
                     const float* __restrict__ Bm,
                     const float* __restrict__ Gm,
                     const float* __restrict__ Sm,
                     const float* __restrict__ bias,
                     const int* __restrict__ P,
                     float* __restrict__ out)
{
    // [ihrel][iw][ch], ch contiguous -> conflict-free patch reads. 49152 B.
    __shared__ uint16_t s_in[3 * 32 * 256];
    // swizzled FWHT exchange buffer. 16384 B. Total LDS = 65536 -> 2 blocks/CU.
    __shared__ float buf[4096];

    const int t  = threadIdx.x;
    const int t1 = t >> 4, t0 = t & 15;
    const int b  = blockIdx.x >> 5;
    const int oh = blockIdx.x & 31;

    // ---- stage input rows oh-1..oh+1, all 256 ch, into LDS (coalesced float4)
    #pragma unroll
    for (int i = 0; i < 24; ++i) {
        const int idx   = t + i * 256;       // 6144 16-byte chunks
        const int part  = idx & 7;           // which 16B of the 128B row
        const int ch    = (idx >> 3) & 255;
        const int ihrel = idx >> 11;
        const int ih    = oh - 1 + ihrel;
        float4 ld = make_float4(0.f, 0.f, 0.f, 0.f);  // zero-fill padded rows
        if ((unsigned)ih < 32u) {
            ld = *reinterpret_cast<const float4*>(
                in + ((((size_t)b * 256 + ch) * 32 + ih) * 32 + part * 4));
        }
        const int base = ((ihrel * 32 + part * 4) << 8) | ch;  // transposed scatter
        s_in[base      ] = f2bf(ld.x);
        s_in[base + 256] = f2bf(ld.y);
        s_in[base + 512] = f2bf(ld.z);
        s_in[base + 768] = f2bf(ld.w);
    }

    // ---- per-thread constant preloads (all coalesced)
    float Bv[9];
    #pragma unroll
    for (int r = 0; r < 9; ++r) Bv[r] = Bm[r * 256 + t];
    float Gv[16]; int PAv[16];
    #pragma unroll
    for (int r = 0; r < 16; ++r) {
        Gv[r]  = Gm[r * 256 + t];
        PAv[r] = swz(P[r * 256 + t]);        // pre-swizzled gather addresses
    }
    float Sv[16], Cv[16];
    if (t < 32) {
        #pragma unroll
        for (int r = 0; r < 16; ++r) {
            Sv[r] = Sm[t * 16 + r];
            Cv[r] = bias[t * 16 + r];
        }
    }
    __syncthreads();

    for (int ow = 0; ow < 32; ++ow) {
        float x[16];
        // build x in round-A layout: j = r*256 + t, r = kk = kh*3+kw, ch = t
        #pragma unroll
        for (int r = 0; r < 9; ++r) {
            const int kh = r / 3, kw = r % 3;
            const int iw = ow - 1 + kw;
            float v = 0.f;
            if ((unsigned)iw < 32u) v = bf2f(s_in[((kh * 32 + iw) << 8) | t]);
            x[r] = v * Bv[r];
        }
        #pragma unroll
        for (int r = 9; r < 16; ++r) x[r] = 0.f;  // zero pad 2304..4095 (=r>=9)

        #pragma unroll
        for (int pass = 0; pass < 2; ++pass) {
            h16(x);                       // round A (digit j2: bits 8-11)
            __syncthreads();
            #pragma unroll
            for (int r = 0; r < 16; ++r) buf[swz(256 * r + t)] = x[r];
            __syncthreads();
            #pragma unroll
            for (int r = 0; r < 16; ++r) x[r] = buf[swz(256 * t1 + 16 * r + t0)];
            h16(x);                       // round B (bits 4-7)
            __syncthreads();
            #pragma unroll
            for (int r = 0; r < 16; ++r) buf[swz(256 * t1 + 16 * r + t0)] = x[r];
            __syncthreads();
            #pragma unroll
            for (int r = 0; r < 16; ++r) x[r] = buf[swz(256 * t1 + 16 * t0 + r)];
            h16(x);                       // round C (bits 0-3)
            if (pass == 0) {
                // permutation + G, gather lands directly in round-A layout
                __syncthreads();
                #pragma unroll
                for (int r = 0; r < 16; ++r) buf[swz(256 * t1 + 16 * t0 + r)] = x[r];
                __syncthreads();
                #pragma unroll
                for (int r = 0; r < 16; ++r) x[r] = Gv[r] * buf[PAv[r]];
            }
        }

        // epilogue: thread t<32 holds j = 16t + r for r=0..15 (all j<512)
        if (t < 32) {
            const size_t base = (((size_t)b * 512) + t * 16) * 1024 + oh * 32 + ow;
            #pragma unroll
            for (int r = 0; r < 16; ++r)
                out[base + (size_t)r * 1024] = Sv[r] * x[r] + Cv[r];
        }
    }
}

extern "C" void kernel_launch(void* const* d_in, const int* in_sizes, int n_in,
                              void* d_out, int out_size, void* d_ws, size_t ws_size,
                              hipStream_t stream) {
    const float* in   = (const float*)d_in[0];
    const float* Bm   = (const float*)d_in[1];
    const float* Gm   = (const float*)d_in[2];
    const float* Sm   = (const float*)d_in[3];
    const float* bias = (const float*)d_in[4];
    const int*   P    = (const int*)d_in[5];
    float* out = (float*)d_out;

    dim3 grid(16 * 32);   // (b, oh)
    dim3 block(256);
    fastfood_kernel<<<grid, block, 0, stream>>>(in, Bm, Gm, Sm, bias, P, out);
}

// Round 3
// 197.715 us; speedup vs baseline: 1.0537x; 1.0537x over previous
//
#include <hip/hip_runtime.h>
#include <hip/hip_bf16.h>
#include <stdint.h>

// Fastfood 2D conv, MI355X. fp32 I/O:
// input (16,256,32,32), B/G/S (1,4096), bias (512), P (4096) i32 -> out (16,512,32,32).
// Per pixel: patch j=kk*256+ch (2304, pad 4096), *B, FWHT4096, perm P, *G, FWHT4096,
// *S[0:512]+bias.
//
// R2 structure: each block = (b, oh); processes pixel PAIRS (ow=p, p+16) with both
// pixels packed bf16x2 into the 4096-word swizzled LDS exchange buffer (same
// conflict-free XOR swizzle as R1 -> LDS instr per pixel halves). Butterflies on
// float2 -> v_pk_add_f32. Epilogue: LDS redistribution so thread t holds channels
// 2t,2t+1 -> coalesced float2 stores to ws in PIXEL-MAJOR layout (no write
// amplification); kernel2 transposes to channel-major with line-clean 128B rows.

__device__ __forceinline__ float bf2f(uint16_t u) {
    union { uint32_t i; float f; } c; c.i = ((uint32_t)u) << 16; return c.f;
}
__device__ __forceinline__ uint16_t f2bf(float f) {  // RNE
    uint32_t u = __float_as_uint(f);
    return (uint16_t)((u + 0x7FFFu + ((u >> 16) & 1u)) >> 16);
}
__device__ __forceinline__ int swz(int j) {
    return j ^ ((j >> 5) & 7) ^ (((j >> 8) & 1) * 24) ^ (((j >> 9) & 1) * 8);
}
__device__ __forceinline__ uint32_t pk2(float a, float b) {
    __hip_bfloat162 h = __float22bfloat162_rn(make_float2(a, b));
    union { __hip_bfloat162 h; uint32_t u; } c; c.h = h; return c.u;
}
__device__ __forceinline__ float2 unpk(uint32_t u) {
    return make_float2(__uint_as_float(u << 16), __uint_as_float(u & 0xFFFF0000u));
}
__device__ __forceinline__ void h16p(float2* x) {
    #pragma unroll
    for (int h = 1; h < 16; h <<= 1) {
        #pragma unroll
        for (int g = 0; g < 16; g += 2 * h) {
            #pragma unroll
            for (int u = g; u < g + h; ++u) {
                float2 a = x[u], b = x[u + h];
                x[u]     = make_float2(a.x + b.x, a.y + b.y);  // -> v_pk_add_f32
                x[u + h] = make_float2(a.x - b.x, a.y - b.y);
            }
        }
    }
}

__global__ __launch_bounds__(256, 2)
void fastfood_kernel(const float* __restrict__ in,
                     const float* __restrict__ Bm,
                     const float* __restrict__ Gm,
                     const float* __restrict__ Sm,
                     const float* __restrict__ bias,
                     const int* __restrict__ P,
                     float* __restrict__ ws,
                     float* __restrict__ out,   // used only when direct!=0
                     int direct)
{
    __shared__ uint16_t s_in[3 * 32 * 256];   // [ihrel][iw][ch] bf16, 48 KiB
    __shared__ uint32_t buf[4096];            // swizzled bf16x2 exchange, 16 KiB

    const int t  = threadIdx.x;
    const int t1 = t >> 4, t0 = t & 15;
    const int b  = blockIdx.x >> 5;
    const int oh = blockIdx.x & 31;

    // ---- stage input rows oh-1..oh+1 into LDS (coalesced float4)
    #pragma unroll
    for (int i = 0; i < 24; ++i) {
        const int idx   = t + i * 256;
        const int part  = idx & 7;
        const int ch    = (idx >> 3) & 255;
        const int ihrel = idx >> 11;
        const int ih    = oh - 1 + ihrel;
        float4 ld = make_float4(0.f, 0.f, 0.f, 0.f);
        if ((unsigned)ih < 32u) {
            ld = *reinterpret_cast<const float4*>(
                in + ((((size_t)b * 256 + ch) * 32 + ih) * 32 + part * 4));
        }
        const int base = ((ihrel * 32 + part * 4) << 8) | ch;
        s_in[base      ] = f2bf(ld.x);
        s_in[base + 256] = f2bf(ld.y);
        s_in[base + 512] = f2bf(ld.z);
        s_in[base + 768] = f2bf(ld.w);
    }

    // ---- constants
    float Bv[9];
    #pragma unroll
    for (int r = 0; r < 9; ++r) Bv[r] = Bm[r * 256 + t];
    float Gv[16]; int PAv[16];
    #pragma unroll
    for (int r = 0; r < 16; ++r) {
        Gv[r]  = Gm[r * 256 + t];
        PAv[r] = swz(P[r * 256 + t]);
    }
    const float S0 = Sm[2 * t], S1 = Sm[2 * t + 1];
    const float C0 = bias[2 * t], C1 = bias[2 * t + 1];
    __syncthreads();

    for (int p = 0; p < 16; ++p) {            // pixel pair (ow=p, ow=p+16)
        float2 x[16];
        #pragma unroll
        for (int r = 0; r < 9; ++r) {
            const int kh = r / 3, kw = r % 3;
            const int iw = p - 1 + kw, jw = iw + 16;
            float v0 = 0.f, v1 = 0.f;
            if ((unsigned)iw < 32u) v0 = bf2f(s_in[((kh * 32 + iw) << 8) | t]);
            if ((unsigned)jw < 32u) v1 = bf2f(s_in[((kh * 32 + jw) << 8) | t]);
            x[r] = make_float2(v0 * Bv[r], v1 * Bv[r]);
        }
        #pragma unroll
        for (int r = 9; r < 16; ++r) x[r] = make_float2(0.f, 0.f);

        #pragma unroll
        for (int pass = 0; pass < 2; ++pass) {
            h16p(x);                          // round A
            __syncthreads();
            #pragma unroll
            for (int r = 0; r < 16; ++r) buf[swz(256 * r + t)] = pk2(x[r].x, x[r].y);
            __syncthreads();
            #pragma unroll
            for (int r = 0; r < 16; ++r) x[r] = unpk(buf[swz(256 * t1 + 16 * r + t0)]);
            h16p(x);                          // round B
            __syncthreads();
            #pragma unroll
            for (int r = 0; r < 16; ++r) buf[swz(256 * t1 + 16 * r + t0)] = pk2(x[r].x, x[r].y);
            __syncthreads();
            #pragma unroll
            for (int r = 0; r < 16; ++r) x[r] = unpk(buf[swz(256 * t1 + 16 * t0 + r)]);
            h16p(x);                          // round C
            if (pass == 0) {                  // permutation + G (gather -> A-layout)
                __syncthreads();
                #pragma unroll
                for (int r = 0; r < 16; ++r) buf[swz(256 * t1 + 16 * t0 + r)] = pk2(x[r].x, x[r].y);
                __syncthreads();
                #pragma unroll
                for (int r = 0; r < 16; ++r) {
                    float2 v = unpk(buf[PAv[r]]);
                    x[r] = make_float2(Gv[r] * v.x, Gv[r] * v.y);
                }
            }
        }

        // ---- redistribute outputs: j = 16t + r lives in t<32; give thread t oc=2t,2t+1
        __syncthreads();
        float* bufF = reinterpret_cast<float*>(buf);  // fp32 staging (1024 floats)
        if (t < 32) {
            #pragma unroll
            for (int r = 0; r < 16; ++r) {
                const int a = 16 * t + (r ^ (t & 15));  // 2-way max bank aliasing
                bufF[a]       = x[r].x;
                bufF[a + 512] = x[r].y;
            }
        }
        __syncthreads();
        const int a0 = (2 * t) ^ ((t >> 3) & 15), a1 = a0 ^ 1;
        const float o00 = S0 * bufF[a0]       + C0;   // oc=2t,   ow=p
        const float o01 = S1 * bufF[a1]       + C1;   // oc=2t+1, ow=p
        const float o10 = S0 * bufF[a0 + 512] + C0;   // oc=2t,   ow=p+16
        const float o11 = S1 * bufF[a1 + 512] + C1;   // oc=2t+1, ow=p+16

        if (!direct) {
            const int pix0 = ((b * 32 + oh) * 32 + p);
            *reinterpret_cast<float2*>(ws + (size_t)pix0 * 512 + 2 * t)
                = make_float2(o00, o01);
            *reinterpret_cast<float2*>(ws + (size_t)(pix0 + 16) * 512 + 2 * t)
                = make_float2(o10, o11);
        } else {
            const size_t r0 = ((size_t)b * 512 + 2 * t) * 1024 + oh * 32;
            out[r0 + p]            = o00;
            out[r0 + 1024 + p]     = o01;
            out[r0 + p + 16]       = o10;
            out[r0 + 1024 + p + 16] = o11;
        }
    }
}

// ws (b,oh,ow,oc) -> out (b,oc,oh,ow). Per-lane 128B channel rows: lines fully dirty.
__global__ __launch_bounds__(256)
void transpose_kernel(const float* __restrict__ ws, float* __restrict__ out)
{
    const int t  = threadIdx.x;
    const int b  = blockIdx.x >> 5;
    const int oh = blockIdx.x & 31;
    const float* src = ws + (size_t)((b * 32 + oh) * 32) * 512;  // [ow][oc]
    #pragma unroll
    for (int c = 0; c < 2; ++c) {
        const int oc = 2 * t + c;
        float* dst = out + ((size_t)b * 512 + oc) * 1024 + oh * 32;
        #pragma unroll
        for (int g = 0; g < 8; ++g) {
            float4 v;
            v.x = src[(4 * g + 0) * 512 + oc];
            v.y = src[(4 * g + 1) * 512 + oc];
            v.z = src[(4 * g + 2) * 512 + oc];
            v.w = src[(4 * g + 3) * 512 + oc];
            *reinterpret_cast<float4*>(dst + 4 * g) = v;
        }
    }
}

extern "C" void kernel_launch(void* const* d_in, const int* in_sizes, int n_in,
                              void* d_out, int out_size, void* d_ws, size_t ws_size,
                              hipStream_t stream) {
    const float* in   = (const float*)d_in[0];
    const float* Bm   = (const float*)d_in[1];
    const float* Gm   = (const float*)d_in[2];
    const float* Sm   = (const float*)d_in[3];
    const float* bias = (const float*)d_in[4];
    const int*   P    = (const int*)d_in[5];
    float* out = (float*)d_out;
    float* ws  = (float*)d_ws;

    const size_t need = (size_t)16 * 32 * 32 * 512 * 4;  // 33.5 MB pixel-major staging
    const int direct = (ws_size < need) ? 1 : 0;

    dim3 grid(16 * 32), block(256);
    fastfood_kernel<<<grid, block, 0, stream>>>(in, Bm, Gm, Sm, bias, P, ws, out, direct);
    if (!direct)
        transpose_kernel<<<grid, block, 0, stream>>>(ws, out);
}